// Round 1
// baseline (487.410 us; speedup 1.0000x reference)
//
#include <hip/hip_runtime.h>

// BuildingModule: B=8192 independent sequential chains, T=1024 steps.
// One thread per batch element. Register double-buffer of 8 u-rows
// (16 float4 loads in flight per lane) to hide HBM latency with only
// 128 waves of parallelism. block=64, grid=128 -> 1 wave per CU on 128 CUs.

namespace {
constexpr int T = 1024;
constexpr int ROWS_PER_BLK = 8;           // u rows per prefetch block
constexpr int NBLK = T / ROWS_PER_BLK;    // 128 blocks (block 127 = tail)
}

__global__ __launch_bounds__(64, 1) void bm_fwd(
    const float* __restrict__ x0p,   // (B,3)
    const float* __restrict__ up,    // (B,T,8)
    const float* __restrict__ lamp,  // (14)
    float* __restrict__ outp)        // (B,T,3)
{
    const int b = blockIdx.x * 64 + threadIdx.x;

    // lam -> exponentials (uniform across threads; precise expf, done once)
    float e[14];
#pragma unroll
    for (int i = 0; i < 14; ++i) e[i] = expf(lamp[i]);
    const float e12 = e[0], e23 = e[1];
    const float ee0 = e[2], ee1 = e[3], ee2 = e[4];
    const float es0 = e[5], es1 = e[6], es2 = e[7];
    const float eh0 = e[8], eh1 = e[9], eh2 = e[10];
    const float ec0 = e[11], ec1 = e[12], ec2 = e[13];

    // H / C, precomputed (H=60)
    const float hc0 = 60.0f / 10665991.0f;
    const float hc1 = 60.0f / 27000000.0f;
    const float hc2 = 60.0f / 7953253.0f;

    float X0 = x0p[3 * b + 0];
    float X1 = x0p[3 * b + 1];
    float X2 = x0p[3 * b + 2];

    const float4* __restrict__ ub = (const float4*)(up + (size_t)b * (T * 8));
    float* __restrict__ ob = outp + (size_t)b * (T * 3);

    float4 A[2 * ROWS_PER_BLK], B[2 * ROWS_PER_BLK];

    auto loadblk = [&](float4* buf, int j) {
        const float4* src = ub + j * (2 * ROWS_PER_BLK);
#pragma unroll
        for (int i = 0; i < 2 * ROWS_PER_BLK; ++i) buf[i] = src[i];
    };

    // One scan step. Writes output index s (the PREVIOUS step's state, with
    // the invalid mask from row s's u0), then advances state using u row s.
    auto step = [&](const float4& p, const float4& q, int s, bool check) {
        // p = (u0, u1, h0, h1), q = (h2, c0, c1, c2)
        if (check) {
            const bool bad = (p.x < 1e-6f);
            ob[3 * s + 0] = bad ? -1.0f : X0;
            ob[3 * s + 1] = bad ? -1.0f : X1;
            ob[3 * s + 2] = bad ? -1.0f : X2;
        } else {  // s == 0: output 0 is x0 unconditionally
            ob[0] = X0; ob[1] = X1; ob[2] = X2;
        }
        const float i0 = __builtin_amdgcn_rcpf(X0);
        const float i1 = __builtin_amdgcn_rcpf(X1);
        const float i2 = __builtin_amdgcn_rcpf(X2);
        const float iu = __builtin_amdgcn_rcpf(p.x);
        const float d12 = i0 - i1;
        const float d23 = i1 - i2;
        const float t12 = e12 * d12;
        const float t23 = e23 * d23;
        const float a0 = t12 * X1;
        const float a1 = t23 * X2 - t12 * X0;
        const float a2 = -(t23 * X1);
        const float b0 = ee0 * (i0 - iu) * p.x + es0 * p.y + eh0 * p.z + ec0 * q.y;
        const float b1 = ee1 * (i1 - iu) * p.x + es1 * p.y + eh1 * p.w + ec1 * q.z;
        const float b2 = ee2 * (i2 - iu) * p.x + es2 * p.y + eh2 * q.x + ec2 * q.w;
        // exp(z) = exp2(z * log2(e)) via the fast HW exp
        X0 = X0 * __expf(hc0 * (a0 + b0));
        X1 = X1 * __expf(hc1 * (a1 + b1));
        X2 = X2 * __expf(hc2 * (a2 + b2));
    };

    auto procblk = [&](const float4* buf, int j, bool first) {
#pragma unroll
        for (int i = 0; i < ROWS_PER_BLK; ++i) {
            const int s = j * ROWS_PER_BLK + i;
            step(buf[2 * i], buf[2 * i + 1], s, !(first && i == 0));
        }
    };

    // Software pipeline: prefetch block j+1 while computing block j.
    loadblk(A, 0);
    loadblk(B, 1);
    procblk(A, 0, true);          // block 0 (step 0 writes out[0] = x0)
    for (int j = 1; j < NBLK - 1; j += 2) {   // j = 1,3,...,125 -> blocks 1..126
        loadblk(A, j + 1);
        procblk(B, j, false);
        loadblk(B, j + 2);        // j=125 -> loads block 127 (valid, rows 1016..1023)
        procblk(A, j + 1, false);
    }
    // Tail: block 127 holds rows 1016..1023 -> 7 steps (1016..1022), then the
    // final output index 1023 masked by u[1023][0] (= B[14].x).
#pragma unroll
    for (int i = 0; i < ROWS_PER_BLK - 1; ++i) {
        const int s = (NBLK - 1) * ROWS_PER_BLK + i;
        step(B[2 * i], B[2 * i + 1], s, true);
    }
    {
        const bool bad = (B[2 * (ROWS_PER_BLK - 1)].x < 1e-6f);
        ob[3 * (T - 1) + 0] = bad ? -1.0f : X0;
        ob[3 * (T - 1) + 1] = bad ? -1.0f : X1;
        ob[3 * (T - 1) + 2] = bad ? -1.0f : X2;
    }
}

extern "C" void kernel_launch(void* const* d_in, const int* in_sizes, int n_in,
                              void* d_out, int out_size, void* d_ws, size_t ws_size,
                              hipStream_t stream) {
    const float* x0  = (const float*)d_in[0];   // (B,3)
    const float* u   = (const float*)d_in[1];   // (B,T,8)
    const float* lam = (const float*)d_in[2];   // (14)
    float* out = (float*)d_out;                 // (B,T,3)

    const int B = in_sizes[0] / 3;              // 8192; in_sizes[1]/(8*B) == 1024 == T
    dim3 grid(B / 64), block(64);
    hipLaunchKernelGGL(bm_fwd, grid, block, 0, stream, x0, u, lam, out);
}

// Round 2
// 436.672 us; speedup vs baseline: 1.1162x; 1.1162x over previous
//
#include <hip/hip_runtime.h>

// BuildingModule: B=8192 sequential chains, T=1024 steps, u:(B,T,8) f32, out:(B,T,3) f32.
//
// R2 design: 8 lanes per chain ("phases"). 65536 threads = 1024 waves -> 4 waves/CU
// on all 256 CUs (R1 had 128 waves on 128 CUs). Per 8-step block:
//   - lane loads ONE u-row (2x float4): per wave-instr 8 chains x 8 rows dense
//     (256B contiguous/chain) vs R1's 64-way scatter.
//   - owner lane pre-reduces its row to {u0, P0,P1,P2} where
//     P_k = es_k*u1 + eh_k*h_k + ec_k*c_k - ee_k   (using (1/x-1/u0)*u0 = u0/x - 1,
//     which also removes the rcp(u0) from every step).
//   - broadcasts via ds_bpermute, all hoisted to block start (off critical path).
//   - every lane runs the recurrence redundantly (VALU is wave-wide anyway);
//     lane captures the output of step (8j+phase) pre-update; 3 stores/block,
//     96B-contiguous per chain.

#if __has_builtin(__builtin_amdgcn_exp2f)
#define EXP2F(x) __builtin_amdgcn_exp2f(x)
#else
#define EXP2F(x) __expf((x) * 0.69314718056f)   // fallback: exp(z*ln2) == 2^z
#endif

namespace {
constexpr int T = 1024;
constexpr int NBLK = T / 8;   // 128 blocks of 8 rows
constexpr float LOG2E = 1.4426950408889634f;
}

__device__ __forceinline__ float bcast8(float v, int idx) {
    return __int_as_float(__builtin_amdgcn_ds_bpermute(idx, __float_as_int(v)));
}

__global__ __launch_bounds__(256, 1) void bm_fwd(
    const float* __restrict__ x0p,   // (B,3)
    const float* __restrict__ up,    // (B,T,8)
    const float* __restrict__ lamp,  // (14)
    float* __restrict__ outp)        // (B,T,3)
{
    const int tid   = blockIdx.x * 256 + threadIdx.x;
    const int chain = tid >> 3;
    const int phase = tid & 7;
    // ds_bpermute byte-index of this lane's group-of-8 base (within the wave)
    const int idx_base = (threadIdx.x & 56) << 2;

    // lam -> exponentials (uniform; precise expf once)
    float e[14];
#pragma unroll
    for (int i = 0; i < 14; ++i) e[i] = expf(lamp[i]);
    const float e12 = e[0], e23 = e[1];
    const float ee0 = e[2], ee1 = e[3], ee2 = e[4];
    const float es0 = e[5], es1 = e[6], es2 = e[7];
    const float eh0 = e[8], eh1 = e[9], eh2 = e[10];
    const float ec0 = e[11], ec1 = e[12], ec2 = e[13];

    // H/C pre-folded into log2 domain (EXP2F(hc_k * z) == exp((H/C_k) * z))
    const float hc0 = (60.0f / 10665991.0f) * LOG2E;
    const float hc1 = (60.0f / 27000000.0f) * LOG2E;
    const float hc2 = (60.0f / 7953253.0f) * LOG2E;

    float X0 = x0p[3 * chain + 0];
    float X1 = x0p[3 * chain + 1];
    float X2 = x0p[3 * chain + 2];

    const float4* __restrict__ ub = (const float4*)(up + (size_t)chain * (T * 8));
    float* __restrict__ ob = outp + (size_t)chain * (T * 3);

    float4 A0, A1, B0, B1;  // double-buffered: this lane's row of a block (32B)

    auto loadA = [&](int j) {
        const float4* s = ub + (size_t)(8 * j + phase) * 2;
        A0 = s[0]; A1 = s[1];
    };
    auto loadB = [&](int j) {
        const float4* s = ub + (size_t)(8 * j + phase) * 2;
        B0 = s[0]; B1 = s[1];
    };

    auto procblk = [&](const float4& r0, const float4& r1, int j, bool first) {
        // Owner-side pre-reduction of my row (rows 8j+phase)
        const float u0 = r0.x;
        const float Pk0 = fmaf(ec0, r1.y, fmaf(eh0, r0.z, fmaf(es0, r0.y, -ee0)));
        const float Pk1 = fmaf(ec1, r1.z, fmaf(eh1, r0.w, fmaf(es1, r0.y, -ee1)));
        const float Pk2 = fmaf(ec2, r1.w, fmaf(eh2, r1.x, fmaf(es2, r0.y, -ee2)));

        // Broadcast all 8 phases' values up front (off the critical chain)
        float W[8], Q0[8], Q1[8], Q2[8];
#pragma unroll
        for (int i = 0; i < 8; ++i) {
            const int idx = idx_base + (i << 2);
            W[i]  = bcast8(u0, idx);
            Q0[i] = bcast8(Pk0, idx);
            Q1[i] = bcast8(Pk1, idx);
            Q2[i] = bcast8(Pk2, idx);
        }

        float O0 = 0.0f, O1 = 0.0f, O2 = 0.0f;
#pragma unroll
        for (int i = 0; i < 8; ++i) {
            // Capture output index 8j+i = state BEFORE this row's update,
            // masked by this row's u0 (except output 0, which is x0 unmasked).
            const bool bad = (W[i] < 1e-6f) && !(first && i == 0);
            if (phase == i) {
                O0 = bad ? -1.0f : X0;
                O1 = bad ? -1.0f : X1;
                O2 = bad ? -1.0f : X2;
            }
            // Advance state with row 8j+i
            const float i0 = __builtin_amdgcn_rcpf(X0);
            const float i1 = __builtin_amdgcn_rcpf(X1);
            const float i2 = __builtin_amdgcn_rcpf(X2);
            const float t12 = e12 * (i0 - i1);
            const float t23 = e23 * (i1 - i2);
            const float b0 = fmaf(ee0, W[i] * i0, Q0[i]);
            const float b1 = fmaf(ee1, W[i] * i1, Q1[i]);
            const float b2 = fmaf(ee2, W[i] * i2, Q2[i]);
            const float z0 = fmaf(t12, X1, b0);
            const float z1 = fmaf(t23, X2, fmaf(-t12, X0, b1));
            const float z2 = fmaf(-t23, X1, b2);
            X0 *= EXP2F(hc0 * z0);
            X1 *= EXP2F(hc1 * z1);
            X2 *= EXP2F(hc2 * z2);
        }
        // Store output row 8j+phase (per instr: 8 chains x 8 phases, 96B/chain)
        float* o = ob + (size_t)(8 * j + phase) * 3;
        o[0] = O0; o[1] = O1; o[2] = O2;
    };

    // Software pipeline: load block j+1 while computing block j
    loadA(0);
    loadB(1);
    procblk(A0, A1, 0, true);
    for (int j = 1; j < NBLK - 1; j += 2) {
        loadA(j + 1);
        procblk(B0, B1, j, false);
        loadB(j + 2);
        procblk(A0, A1, j + 1, false);
    }
    procblk(B0, B1, NBLK - 1, false);
}

extern "C" void kernel_launch(void* const* d_in, const int* in_sizes, int n_in,
                              void* d_out, int out_size, void* d_ws, size_t ws_size,
                              hipStream_t stream) {
    const float* x0  = (const float*)d_in[0];   // (B,3)
    const float* u   = (const float*)d_in[1];   // (B,T,8)
    const float* lam = (const float*)d_in[2];   // (14)
    float* out = (float*)d_out;                 // (B,T,3)

    const int B = in_sizes[0] / 3;              // 8192
    const int threads = B * 8;                  // 8 lanes per chain
    dim3 grid(threads / 256), block(256);
    hipLaunchKernelGGL(bm_fwd, grid, block, 0, stream, x0, u, lam, out);
}

// Round 3
// 413.892 us; speedup vs baseline: 1.1776x; 1.0550x over previous
//
#include <hip/hip_runtime.h>

// BuildingModule: B=8192 sequential chains, T=1024 steps, u:(B,T,8) f32, out:(B,T,3) f32.
//
// R3: 8 lanes/chain (coalesced loads), redundant compute, but broadcast via
// per-block LDS round-trip instead of per-step ds_bpermute (R2's hidden cost:
// compiler sank 4 bpermutes + lgkmcnt(0) into every step ~160 cyc/step).
// Owner lane pre-folds its row into 6 floats (H/C, log2e, ee all pre-folded):
//   E_k = hc_k*ee_k*u0,  G_k = hc_k*(es_k*u1 + eh_k*h_k + ec_k*c_k - ee_k)
//   step: z_k = (F_*·d)·X_± + (E_k·i_k + G_k);  X_k *= exp2(z_k)
// 2 LDS writes + 16 hoisted conflict-free reads per 8-step block; one lgkm
// wait per block. Chains' 8 lanes are within one wave -> no barriers.
// Global u prefetch 2 blocks ahead in static register slots.

#if __has_builtin(__builtin_amdgcn_exp2f)
#define EXP2F(x) __builtin_amdgcn_exp2f(x)
#else
#define EXP2F(x) __expf((x) * 0.69314718056f)
#endif

namespace {
constexpr int T = 1024;
constexpr int NBLK = T / 8;           // 128 blocks of 8 rows
constexpr float LOG2E = 1.4426950408889634f;
constexpr int CH_STRIDE = 68;         // floats per chain LDS region (8 rows * 8 + 4 pad)
}

__global__ __launch_bounds__(256, 1) void bm_fwd(
    const float* __restrict__ x0p,   // (B,3)
    const float* __restrict__ up,    // (B,T,8)
    const float* __restrict__ lamp,  // (14)
    float* __restrict__ outp)        // (B,T,3)
{
    // 32 chains/WG * 272B, XOR-swizzled row slots: row r of chain g -> slot (r^g).
    // region base bank = 4g, slot shifts 8 banks -> reads conflict-free (2-way max).
    __shared__ float lds[32 * CH_STRIDE];

    const int tid   = blockIdx.x * 256 + threadIdx.x;
    const int chain = tid >> 3;
    const int phase = tid & 7;
    const int g     = (threadIdx.x >> 3) & 7;   // group within wave
    float* __restrict__ region = lds + (threadIdx.x >> 3) * CH_STRIDE;
    float* __restrict__ wslot  = region + ((phase ^ g) << 3);

    // lam -> exponentials (uniform; precise expf once per thread)
    float e[14];
#pragma unroll
    for (int i = 0; i < 14; ++i) e[i] = expf(lamp[i]);
    const float e12 = e[0], e23 = e[1];

    // H/C in log2 domain, folded into every coefficient
    const float hc0 = (60.0f / 10665991.0f) * LOG2E;
    const float hc1 = (60.0f / 27000000.0f) * LOG2E;
    const float hc2 = (60.0f / 7953253.0f) * LOG2E;
    const float F12_0 = hc0 * e12, F12_1 = hc1 * e12;
    const float F23_1 = hc1 * e23, F23_2 = hc2 * e23;
    const float hce0 = hc0 * e[2],  hce1 = hc1 * e[3],  hce2 = hc2 * e[4];
    const float ss0  = hc0 * e[5],  ss1  = hc1 * e[6],  ss2  = hc2 * e[7];
    const float sh0  = hc0 * e[8],  sh1  = hc1 * e[9],  sh2  = hc2 * e[10];
    const float sc0  = hc0 * e[11], sc1  = hc1 * e[12], sc2  = hc2 * e[13];

    float X0 = x0p[3 * chain + 0];
    float X1 = x0p[3 * chain + 1];
    float X2 = x0p[3 * chain + 2];

    const float4* __restrict__ ub = (const float4*)(up + (size_t)chain * (T * 8));
    float* __restrict__ ob = outp + (size_t)chain * (T * 3);

    // one iteration: consume (r0,r1) = my row of block j, then reload them with
    // block j+2 (clamped), LDS-broadcast, compute 8 steps, store my output row.
    auto body = [&](int j, float4& r0, float4& r1) {
        const float my_u0 = r0.x;
        const float E0 = hce0 * r0.x, E1 = hce1 * r0.x, E2 = hce2 * r0.x;
        const float G0 = fmaf(sc0, r1.y, fmaf(sh0, r0.z, fmaf(ss0, r0.y, -hce0)));
        const float G1 = fmaf(sc1, r1.z, fmaf(sh1, r0.w, fmaf(ss1, r0.y, -hce1)));
        const float G2 = fmaf(sc2, r1.w, fmaf(sh2, r1.x, fmaf(ss2, r0.y, -hce2)));
        *(float4*)wslot       = make_float4(E0, E1, E2, G0);
        *(float2*)(wslot + 4) = make_float2(G1, G2);

        // prefetch block j+2 into the just-freed slot (clamped; redundant tail loads ok)
        {
            const int jj = (j + 2 < NBLK) ? (j + 2) : (NBLK - 1);
            const float4* s = ub + (size_t)(((jj << 3) + phase) * 2);
            r0 = s[0]; r1 = s[1];
        }

        // hoisted broadcast reads: all 8 rows (one lgkm wait for the block)
        float4 bA[8]; float2 bB[8];
#pragma unroll
        for (int i = 0; i < 8; ++i) {
            float* p = region + ((i ^ g) << 3);
            bA[i] = *(float4*)p;
            bB[i] = *(float2*)(p + 4);
        }

        float O0 = 0.0f, O1 = 0.0f, O2 = 0.0f;
#pragma unroll
        for (int i = 0; i < 8; ++i) {
            if (phase == i) { O0 = X0; O1 = X1; O2 = X2; }   // state BEFORE row 8j+i
            const float i0 = __builtin_amdgcn_rcpf(X0);
            const float i1 = __builtin_amdgcn_rcpf(X1);
            const float i2 = __builtin_amdgcn_rcpf(X2);
            const float d12 = i0 - i1, d23 = i1 - i2;
            const float z0 = fmaf(F12_0 * d12, X1, fmaf(bA[i].x, i0, bA[i].w));
            const float z1 = fmaf(F23_1 * d23, X2,
                             fmaf(-(F12_1 * d12), X0, fmaf(bA[i].y, i1, bB[i].x)));
            const float z2 = fmaf(-(F23_2 * d23), X1, fmaf(bA[i].z, i2, bB[i].y));
            X0 *= EXP2F(z0);
            X1 *= EXP2F(z1);
            X2 *= EXP2F(z2);
        }

        // store my output row; invalid-mask from my OWN u0 (no broadcast needed);
        // out[0] (j==0,phase==0) is x0 unmasked.
        const bool bad = (my_u0 < 1e-6f) && !((j == 0) & (phase == 0));
        float3 o;
        o.x = bad ? -1.0f : O0;
        o.y = bad ? -1.0f : O1;
        o.z = bad ? -1.0f : O2;
        *(float3*)(ob + (size_t)((j << 3) + phase) * 3) = o;
    };

    // static double slots (no dynamic array indexing -> stays in VGPRs)
    float4 a0, a1, b0, b1;
    {
        const float4* s = ub + (size_t)(phase * 2);
        a0 = s[0]; a1 = s[1];
        const float4* t = ub + (size_t)((8 + phase) * 2);
        b0 = t[0]; b1 = t[1];
    }
    for (int j = 0; j < NBLK; j += 2) {
        body(j,     a0, a1);
        body(j + 1, b0, b1);
    }
}

extern "C" void kernel_launch(void* const* d_in, const int* in_sizes, int n_in,
                              void* d_out, int out_size, void* d_ws, size_t ws_size,
                              hipStream_t stream) {
    const float* x0  = (const float*)d_in[0];   // (B,3)
    const float* u   = (const float*)d_in[1];   // (B,T,8)
    const float* lam = (const float*)d_in[2];   // (14)
    float* out = (float*)d_out;                 // (B,T,3)

    const int B = in_sizes[0] / 3;              // 8192
    const int threads = B * 8;                  // 8 lanes per chain
    dim3 grid(threads / 256), block(256);
    hipLaunchKernelGGL(bm_fwd, grid, block, 0, stream, x0, u, lam, out);
}